// Round 7
// baseline (179.182 us; speedup 1.0000x reference)
//
#include <hip/hip_runtime.h>
#include <cstdint>

typedef unsigned short u16;
typedef __attribute__((ext_vector_type(8))) short short8;
typedef __attribute__((ext_vector_type(8))) _Float16 half8;
typedef __attribute__((ext_vector_type(2))) __fp16 fp16x2;   // cvt_pkrtz return type
typedef __attribute__((ext_vector_type(4))) float f32x4;
typedef __attribute__((ext_vector_type(4))) unsigned short ushort4v;

#if __has_builtin(__builtin_amdgcn_exp2f)
#define EXP2F(x) __builtin_amdgcn_exp2f(x)
#else
#define EXP2F(x) exp2f(x)
#endif

// Explicit drain of async global->LDS DMA (vmcnt) + LDS ops (lgkmcnt) BEFORE
// the barrier. Proven necessary in R4->R5: without it, warm graph replays hit
// a staging race (~2e-3 corruption). Keep at EVERY buffer handoff.
#define SYNC_DRAIN() do { \
  asm volatile("s_waitcnt vmcnt(0) lgkmcnt(0)" ::: "memory"); \
  __syncthreads(); \
} while (0)

// fp32 -> fp16 bits, round-to-nearest-even (v_cvt_f16_f32)
__device__ inline u16 f2h(float f) {
  union { _Float16 h; u16 u; } v;
  v.h = (_Float16)f;
  return v.u;
}

// async global -> LDS, 16B per lane (contiguous landing order only)
__device__ inline void gl2lds16(const void* g, void* l) {
  __builtin_amdgcn_global_load_lds(
      (const __attribute__((address_space(1))) unsigned int*)(unsigned long long)(uintptr_t)g,
      (__attribute__((address_space(3))) unsigned int*)(unsigned int)(uintptr_t)l,
      16, 0, 0);
}

// XOR chunk swizzle: within each 64-elem K-slice of a row, 16B chunk c of row
// r is stored at position c ^ (r & 7). gl2lds staging copies slices verbatim;
// fragment reads at chunk' = (kk*4+lg) ^ (l15&7) are phase-conflict-free.

// ---------------------------------------------------------------- cvt kernel
// Everything converts to FP16 (11-bit mantissa): 8x lower quantization error
// than bf16 at identical MFMA rate.
__global__ __launch_bounds__(256) void cvt_kernel(
    const float* __restrict__ x,
    const float* __restrict__ wq, const float* __restrict__ wk,
    const float* __restrict__ wv, const float* __restrict__ wo,
    u16* __restrict__ xb, u16* __restrict__ wqb, u16* __restrict__ wkb,
    u16* __restrict__ wvb, u16* __restrict__ wob) {
  const int y = blockIdx.y;
  const int Q = 1 << 20;
  const float* src;
  u16* dst;
  if (y < 4)       { src = x + y * Q; dst = xb + y * Q; }
  else if (y == 4) { src = wq; dst = wqb; }
  else if (y == 5) { src = wk; dst = wkb; }
  else if (y == 6) { src = wv; dst = wvb; }
  else             { src = wo; dst = wob; }
  const int i = (blockIdx.x * 256 + threadIdx.x) * 8;
  float4 a = *(const float4*)(src + i);
  float4 b = *(const float4*)(src + i + 4);
  short8 o;
  o[0] = (short)f2h(a.x); o[1] = (short)f2h(a.y);
  o[2] = (short)f2h(a.z); o[3] = (short)f2h(a.w);
  o[4] = (short)f2h(b.x); o[5] = (short)f2h(b.y);
  o[6] = (short)f2h(b.z); o[7] = (short)f2h(b.w);
  const int j = (i & ~63) | (((((i >> 3) & 7) ^ ((i >> 10) & 7))) << 3);
  *(short8*)(dst + j) = o;
}

// ------------------------------------------------------------ QKV projection
// Z-FUSED NT GEMM: x staged once feeds 3 B-panels, 48 MFMA/wave per k-iter.
// grid (16, 32) = 512 blocks, 80 KB LDS -> 2 blocks/CU. Double-buffered
// gl2lds, one barrier per K-iter. All operands FP16.
// Q out: plain [B,NH,S,D], PRE-SCALED by log2(e)/8 (softmax fold).
// K out: [B,NH,S,D] chunk-swizzled by s&7.
// V out: V^T [B,NH,D,Sperm]; key slot within each 64-key block:
//   key = slice*32 + t*16 + quad*4 + r  ->  slot = slice*32 + quad*8 + t*4 + r
// (matches attn's P B-operand key order); chunk-swizzled by d&7.
__global__ __launch_bounds__(256, 2) void gemm_qkv(
    const u16* __restrict__ xb,
    const u16* __restrict__ wqb, const u16* __restrict__ wkb, const u16* __restrict__ wvb,
    const float* __restrict__ bq, const float* __restrict__ bk, const float* __restrict__ bv,
    u16* __restrict__ qo, u16* __restrict__ ko, u16* __restrict__ vto) {
  __shared__ u16 smem[40960];        // As[2][8192] | Bs[2][3][4096] = 80 KB
  u16* As = smem;                    // + p*8192
  u16* Bs = smem + 16384;            // + p*12288 + z*4096
  const int tid = threadIdx.x, lane = tid & 63;
  const int wid = tid >> 6;
  const int l15 = lane & 15, lg = lane >> 4;
  const int m0 = blockIdx.y * 128, n0 = blockIdx.x * 64;
  const int sw = ((l15 & 7) << 3);
  const u16* Wz[3] = {wqb, wkb, wvb};

  f32x4 acc[3][2][4] = {};

  // prologue: stage k0=0 into buffer 0
#pragma unroll
  for (int i = 0; i < 4; ++i) {
    int c = i * 256 + tid;
    gl2lds16(xb + (m0 + (c >> 3)) * 1024 + (c & 7) * 8, As + c * 8);
  }
#pragma unroll
  for (int z = 0; z < 3; ++z)
#pragma unroll
    for (int i = 0; i < 2; ++i) {
      int c = i * 256 + tid;
      gl2lds16(Wz[z] + (n0 + (c >> 3)) * 1024 + (c & 7) * 8, Bs + z * 4096 + c * 8);
    }

  for (int k0 = 0; k0 < 1024; k0 += 64) {
    const int p = (k0 >> 6) & 1;
    SYNC_DRAIN();  // all waves' staging into buf p landed -> buf p ready
    if (k0 < 960) {
      u16* An = As + (1 - p) * 8192;
      u16* Bn = Bs + (1 - p) * 12288;
#pragma unroll
      for (int i = 0; i < 4; ++i) {
        int c = i * 256 + tid;
        gl2lds16(xb + (m0 + (c >> 3)) * 1024 + k0 + 64 + (c & 7) * 8, An + c * 8);
      }
#pragma unroll
      for (int z = 0; z < 3; ++z)
#pragma unroll
        for (int i = 0; i < 2; ++i) {
          int c = i * 256 + tid;
          gl2lds16(Wz[z] + (n0 + (c >> 3)) * 1024 + k0 + 64 + (c & 7) * 8, Bn + z * 4096 + c * 8);
        }
    }
    const u16* Ap = As + p * 8192;
    const u16* Bp = Bs + p * 12288;
#pragma unroll
    for (int kk = 0; kk < 2; ++kk) {
      half8 af[2], bf[3][4];
#pragma unroll
      for (int mb = 0; mb < 2; ++mb)
        af[mb] = *(const half8*)(Ap + (wid * 32 + mb * 16 + l15) * 64 + ((((kk * 4 + lg) << 3)) ^ sw));
#pragma unroll
      for (int z = 0; z < 3; ++z)
#pragma unroll
        for (int nb = 0; nb < 4; ++nb)
          bf[z][nb] = *(const half8*)(Bp + z * 4096 + (nb * 16 + l15) * 64 + ((((kk * 4 + lg) << 3)) ^ sw));
#pragma unroll
      for (int z = 0; z < 3; ++z)
#pragma unroll
        for (int mb = 0; mb < 2; ++mb)
#pragma unroll
          for (int nb = 0; nb < 4; ++nb)
            acc[z][mb][nb] = __builtin_amdgcn_mfma_f32_16x16x32_f16(af[mb], bf[z][nb], acc[z][mb][nb], 0, 0, 0);
    }
  }

  const float cexp = 0.18033688011112042f;  // log2(e)/8 folded into Q

  // Q epilogue (plain layout, pre-scaled)
#pragma unroll
  for (int mb = 0; mb < 2; ++mb)
#pragma unroll
    for (int nb = 0; nb < 4; ++nb)
#pragma unroll
      for (int r = 0; r < 4; ++r) {
        int m = m0 + wid * 32 + mb * 16 + lg * 4 + r;  // b*2048 + s
        int n = n0 + nb * 16 + l15;                    // h*64 + d
        float v = (acc[0][mb][nb][r] + bq[n]) * cexp;
        int b = m >> 11, s = m & 2047, hh = n >> 6, d = n & 63;
        qo[((b * 16 + hh) * 2048 + s) * 64 + d] = f2h(v);
      }

  // K epilogue (chunk-swizzled by s&7)
#pragma unroll
  for (int mb = 0; mb < 2; ++mb)
#pragma unroll
    for (int nb = 0; nb < 4; ++nb)
#pragma unroll
      for (int r = 0; r < 4; ++r) {
        int m = m0 + wid * 32 + mb * 16 + lg * 4 + r;
        int n = n0 + nb * 16 + l15;
        float v = acc[1][mb][nb][r] + bk[n];
        int b = m >> 11, s = m & 2047, hh = n >> 6, d = n & 63;
        int dcol = (((d >> 3) ^ (s & 7)) << 3) | (d & 7);
        ko[((b * 16 + hh) * 2048 + s) * 64 + dcol] = f2h(v);
      }

  // V epilogue: wave-pair shared 64(d) x 72 transpose buffers, slot order per
  // the attn B-operand key permutation, then coalesced 16B global stores.
  SYNC_DRAIN();  // all waves done with As/Bs (LDS reads + any DMA drained)
  {
    u16* wbuf = smem + (wid >> 1) * 4608;
#pragma unroll
    for (int mb = 0; mb < 2; ++mb)
#pragma unroll
      for (int nb = 0; nb < 4; ++nb) {
        int n = n0 + nb * 16 + l15;
        float bn = bv[n];
        int dl = nb * 16 + l15;
#pragma unroll
        for (int r = 0; r < 4; ++r) {
          // key s64 = (wid&1)*32 + mb*16 + lg*4 + r  (slice=wid&1, t=mb, quad=lg)
          int sig = (wid & 1) * 32 + lg * 8 + mb * 4 + r;
          wbuf[dl * 72 + sig] = f2h(acc[2][mb][nb][r] + bn);
        }
      }
    SYNC_DRAIN();  // cross-wave transpose complete
    int hh = n0 >> 6;
    int bb = m0 >> 11;
    int sbase = m0 & 2047;
#pragma unroll
    for (int i = 0; i < 4; ++i) {
      int idx = i * 256 + tid;           // 1024 chunks = 2 bufs x 64 x 8
      int p2 = idx >> 9, rem = idx & 511;
      int dl = rem >> 3, c = rem & 7;
      short8 vv = *(const short8*)(smem + p2 * 4608 + dl * 72 + c * 8);
      int cs = c ^ (dl & 7);             // chunk swizzle by d&7
      *(short8*)(vto + ((bb * 16 + hh) * 64 + dl) * 2048 + sbase + p2 * 64 + cs * 8) = vv;
    }
  }
}

// ---------------------------------------------------------------- attention
// TRANSPOSED dataflow (unchanged math): S^T = K·Q^T, P = exp2 in-register,
// O^T = V^T·P, l via ones. FP16; cvt_pkrtz packing; SP overlays KV.
// OCCUPANCY RESTRUCTURE (R6 post-mortem: grid size, not LDS, caps residency):
// 64 q-rows per block, 2 waves (128 thr), grid (16,32,2) = 1024 blocks ->
// 4 independent blocks/CU (was 2). Same total waves/CU (8) but 4 independent
// kt-chains interleave across barriers, and each barrier syncs 2 waves not 4.
// Per-wave work is byte-identical to before (32 q-rows each).
__global__ __launch_bounds__(128, 2) void attn_kernel(
    const u16* __restrict__ qg, const u16* __restrict__ kg,
    const u16* __restrict__ vtg, u16* __restrict__ ctxg) {
  const int h = blockIdx.x, qt = blockIdx.y, b = blockIdx.z;
  const int bh = b * 16 + h;
  const u16* Qg = qg + (bh * 2048 + qt * 64) * 64;
  const u16* Kg = kg + bh * 2048 * 64;
  const u16* Vg = vtg + bh * 64 * 2048;

  __shared__ u16 KV[2][8192];    // 32 KB: [p][0:4096)=K, [p][4096:8192)=V^T
  u16* SP = &KV[0][0];           // epilogue overlay: 64*72 u16 = 9 KB < 32 KB

  const int tid = threadIdx.x, lane = tid & 63, wid = tid >> 6;  // wid in {0,1}
  const int l15 = lane & 15, lg = lane >> 4;
  const int row0 = wid * 32;     // this wave's 32 query rows (of the block's 64)
  const int sw = ((l15 & 7) << 3);

  // Q fragments direct from global (pre-scaled; reused all 32 kt).
  // Used as B operand: (n = q = l15, k = d = lg*8.. + kk*32) — same layout.
  half8 qf[2][2];
#pragma unroll
  for (int qtile = 0; qtile < 2; ++qtile)
#pragma unroll
    for (int kk = 0; kk < 2; ++kk)
      qf[qtile][kk] = *(const half8*)(Qg + (row0 + qtile * 16 + l15) * 64 + kk * 32 + lg * 8);

  half8 ones8;
#pragma unroll
  for (int j = 0; j < 8; ++j) ones8[j] = (_Float16)1.0f;

  // prologue: stage kt=0 into buffer 0 (128 thr: 4+4 chunks of 16B each)
#pragma unroll
  for (int i = 0; i < 4; ++i) {
    int c = i * 128 + tid;
    gl2lds16(Kg + c * 8, &KV[0][c * 8]);
    gl2lds16(Vg + (c >> 3) * 2048 + (c & 7) * 8, &KV[0][4096 + c * 8]);
  }

  f32x4 acc[4][2] = {};   // O^T: [dtile][qtile], C col = q = l15, row = d
  f32x4 accl[2] = {};     // l:  [qtile], all rows identical = l[q=l15]

  for (int kt = 0; kt < 32; ++kt) {
    const int p = kt & 1;
    SYNC_DRAIN();  // all waves' staging into buf p landed -> buf p ready
    if (kt < 31) {
#pragma unroll
      for (int i = 0; i < 4; ++i) {
        int c = i * 128 + tid;
        gl2lds16(Kg + (kt + 1) * 4096 + c * 8, &KV[1 - p][c * 8]);
        gl2lds16(Vg + (c >> 3) * 2048 + (kt + 1) * 64 + (c & 7) * 8, &KV[1 - p][4096 + c * 8]);
      }
    }
    const u16* Ks = &KV[p][0];
    const u16* Vts = &KV[p][4096];

    // S^T = K · Q^T : sc[ktile][qtile], C row = key = lg*4+r, col = q = l15
    f32x4 sc[4][2] = {};
#pragma unroll
    for (int kk = 0; kk < 2; ++kk) {
      half8 kf[4];
#pragma unroll
      for (int ktile = 0; ktile < 4; ++ktile)
        kf[ktile] = *(const half8*)(Ks + (ktile * 16 + l15) * 64 + ((((kk * 4 + lg) << 3)) ^ sw));
#pragma unroll
      for (int ktile = 0; ktile < 4; ++ktile)
#pragma unroll
        for (int qtile = 0; qtile < 2; ++qtile)
          sc[ktile][qtile] = __builtin_amdgcn_mfma_f32_16x16x32_f16(kf[ktile], qf[qtile][kk], sc[ktile][qtile], 0, 0, 0);
    }

    // P = exp2(S^T) packed in-register into B-operand fragments.
    // B element j of slice: key = slice*32 + (j>=4)*16 + quad*4 + (j&3);
    // V^T slots stored in exactly this order.
    half8 pf[2][2];  // [slice][qtile]
#pragma unroll
    for (int sl = 0; sl < 2; ++sl)
#pragma unroll
      for (int qtile = 0; qtile < 2; ++qtile) {
        union { half8 h; fp16x2 h2[4]; } pu;
        float a0 = EXP2F(sc[sl * 2][qtile][0]),     a1 = EXP2F(sc[sl * 2][qtile][1]);
        float a2 = EXP2F(sc[sl * 2][qtile][2]),     a3 = EXP2F(sc[sl * 2][qtile][3]);
        float b0 = EXP2F(sc[sl * 2 + 1][qtile][0]), b1 = EXP2F(sc[sl * 2 + 1][qtile][1]);
        float b2 = EXP2F(sc[sl * 2 + 1][qtile][2]), b3 = EXP2F(sc[sl * 2 + 1][qtile][3]);
        pu.h2[0] = __builtin_amdgcn_cvt_pkrtz(a0, a1);
        pu.h2[1] = __builtin_amdgcn_cvt_pkrtz(a2, a3);
        pu.h2[2] = __builtin_amdgcn_cvt_pkrtz(b0, b1);
        pu.h2[3] = __builtin_amdgcn_cvt_pkrtz(b2, b3);
        pf[sl][qtile] = pu.h;
      }

    // O^T += V^T · P ; l += 1 · P
#pragma unroll
    for (int sl = 0; sl < 2; ++sl) {
      half8 vf[4];
#pragma unroll
      for (int dtile = 0; dtile < 4; ++dtile)
        vf[dtile] = *(const half8*)(Vts + (dtile * 16 + l15) * 64 + ((((sl * 4 + lg) << 3)) ^ sw));
#pragma unroll
      for (int dtile = 0; dtile < 4; ++dtile)
#pragma unroll
        for (int qtile = 0; qtile < 2; ++qtile)
          acc[dtile][qtile] = __builtin_amdgcn_mfma_f32_16x16x32_f16(vf[dtile], pf[sl][qtile], acc[dtile][qtile], 0, 0, 0);
#pragma unroll
      for (int qtile = 0; qtile < 2; ++qtile)
        accl[qtile] = __builtin_amdgcn_mfma_f32_16x16x32_f16(ones8, pf[sl][qtile], accl[qtile], 0, 0, 0);
    }
  }

  // epilogue: KV is dead; SP (64x72) overlays it. Barrier-separated phases.
  SYNC_DRAIN();  // all waves finished reading KV (last tile) before overlay
#pragma unroll
  for (int qtile = 0; qtile < 2; ++qtile) {
    float inv = 1.0f / accl[qtile][0];
#pragma unroll
    for (int dtile = 0; dtile < 4; ++dtile) {
      ushort4v pk;
#pragma unroll
      for (int r = 0; r < 4; ++r)
        pk[r] = f2h(acc[dtile][qtile][r] * inv);   // d = dtile*16 + lg*4 + r
      *(ushort4v*)(SP + (row0 + qtile * 16 + l15) * 72 + dtile * 16 + lg * 4) = pk;
    }
  }
  SYNC_DRAIN();  // SP writes must land before differently-typed reads
#pragma unroll
  for (int i = 0; i < 4; ++i) {
    int idx = i * 64 + lane;               // 256 chunks/wave = 32 rows x 8
    int rl = idx >> 3, c = idx & 7;
    short8 vv = *(const short8*)(SP + (row0 + rl) * 72 + c * 8);
    int s = qt * 64 + row0 + rl;
    int cs = c ^ (s & 7);                  // chunk swizzle by s&7 for gemm_out
    *(short8*)(ctxg + ((long)b * 2048 + s) * 1024 + h * 64 + cs * 8) = vv;
  }
}

// ------------------------------------------------------------ out projection
// out[m,n] = sum_k ctx[m,k]*Wo[n,k] + bo[n], fp32 out, FP16 operands.
// REVERTED to 64x64 tiles (R6 post-mortem: 128x64 halved grid to 512 ->
// 2 blocks/CU resident vs 4; TLP loss outweighed read:MFMA gain).
// grid (16,64) = 1024 blocks, 32 KB LDS -> 4 blocks/CU.
__global__ __launch_bounds__(256) void gemm_out(
    const u16* __restrict__ cb, const u16* __restrict__ wob,
    const float* __restrict__ bo, float* __restrict__ out) {
  __shared__ u16 smem[16384];  // As[2][4096] | Bs[2][4096] = 32 KB
  u16* As = smem;
  u16* Bs = smem + 8192;
  const int tid = threadIdx.x, lane = tid & 63;
  const int wid = tid >> 6;
  const int l15 = lane & 15, lg = lane >> 4;
  const int m0 = blockIdx.y * 64, n0 = blockIdx.x * 64;
  const int sw = ((l15 & 7) << 3);

  f32x4 acc[4] = {};

#pragma unroll
  for (int i = 0; i < 2; ++i) {
    int c = i * 256 + tid;
    gl2lds16(cb  + (m0 + (c >> 3)) * 1024 + (c & 7) * 8, As + c * 8);
    gl2lds16(wob + (n0 + (c >> 3)) * 1024 + (c & 7) * 8, Bs + c * 8);
  }

  for (int k0 = 0; k0 < 1024; k0 += 64) {
    const int p = (k0 >> 6) & 1;
    SYNC_DRAIN();  // all waves' staging into buf p landed -> buf p ready
    if (k0 < 960) {
      u16* An = As + (1 - p) * 4096;
      u16* Bn = Bs + (1 - p) * 4096;
#pragma unroll
      for (int i = 0; i < 2; ++i) {
        int c = i * 256 + tid;
        gl2lds16(cb  + (m0 + (c >> 3)) * 1024 + k0 + 64 + (c & 7) * 8, An + c * 8);
        gl2lds16(wob + (n0 + (c >> 3)) * 1024 + k0 + 64 + (c & 7) * 8, Bn + c * 8);
      }
    }
    const u16* Ap = As + p * 4096;
    const u16* Bp = Bs + p * 4096;
#pragma unroll
    for (int kk = 0; kk < 2; ++kk) {
      half8 af, bf[4];
      af = *(const half8*)(Ap + (wid * 16 + l15) * 64 + ((((kk * 4 + lg) << 3)) ^ sw));
#pragma unroll
      for (int nb = 0; nb < 4; ++nb)
        bf[nb] = *(const half8*)(Bp + (nb * 16 + l15) * 64 + ((((kk * 4 + lg) << 3)) ^ sw));
#pragma unroll
      for (int nb = 0; nb < 4; ++nb)
        acc[nb] = __builtin_amdgcn_mfma_f32_16x16x32_f16(af, bf[nb], acc[nb], 0, 0, 0);
    }
  }

#pragma unroll
  for (int nb = 0; nb < 4; ++nb)
#pragma unroll
    for (int r = 0; r < 4; ++r) {
      int m = m0 + wid * 16 + lg * 4 + r;
      int n = n0 + nb * 16 + l15;
      out[m * 1024 + n] = acc[nb][r] + bo[n];
    }
}

// --------------------------------------------------------------------- launch
extern "C" void kernel_launch(void* const* d_in, const int* in_sizes, int n_in,
                              void* d_out, int out_size, void* d_ws, size_t ws_size,
                              hipStream_t stream) {
  const float* x  = (const float*)d_in[0];
  const float* wq = (const float*)d_in[1];
  const float* bq = (const float*)d_in[2];
  const float* wk = (const float*)d_in[3];
  const float* bk = (const float*)d_in[4];
  const float* wv = (const float*)d_in[5];
  const float* bv = (const float*)d_in[6];
  const float* wo = (const float*)d_in[7];
  const float* bo = (const float*)d_in[8];

  if (ws_size < (size_t)24 * 1024 * 1024 * 2) return;
  u16* xb   = (u16*)d_ws;              // chunk-swizzled fp16
  u16* wqb  = xb  + (4u << 20);        // chunk-swizzled fp16
  u16* wkb  = wqb + (1u << 20);
  u16* wvb  = wkb + (1u << 20);
  u16* wob  = wvb + (1u << 20);
  u16* qb   = wob + (1u << 20);        // plain [B,NH,S,D], pre-scaled fp16
  u16* kb   = qb  + (4u << 20);        // chunk-swizzled [B,NH,S,D] fp16
  u16* vtb  = kb  + (4u << 20);        // V^T [B,NH,D,Sperm], chunk-swizzled fp16
  u16* ctxb = vtb + (4u << 20);        // chunk-swizzled [B,S,H] fp16

  cvt_kernel<<<dim3(512, 8, 1), 256, 0, stream>>>(x, wq, wk, wv, wo, xb, wqb, wkb, wvb, wob);
  gemm_qkv<<<dim3(16, 32, 1), 256, 0, stream>>>(xb, wqb, wkb, wvb, bq, bk, bv, qb, kb, vtb);
  attn_kernel<<<dim3(16, 32, 2), 128, 0, stream>>>(qb, kb, vtb, ctxb);
  gemm_out<<<dim3(16, 64, 1), 256, 0, stream>>>(ctxb, wob, bo, (float*)d_out);
}

// Round 9
// 176.368 us; speedup vs baseline: 1.0160x; 1.0160x over previous
//
#include <hip/hip_runtime.h>
#include <cstdint>

typedef unsigned short u16;
typedef __attribute__((ext_vector_type(8))) short short8;
typedef __attribute__((ext_vector_type(8))) _Float16 half8;
typedef __attribute__((ext_vector_type(2))) __fp16 fp16x2;   // cvt_pkrtz return type
typedef __attribute__((ext_vector_type(4))) float f32x4;
typedef __attribute__((ext_vector_type(4))) unsigned short ushort4v;

#if __has_builtin(__builtin_amdgcn_exp2f)
#define EXP2F(x) __builtin_amdgcn_exp2f(x)
#else
#define EXP2F(x) exp2f(x)
#endif

// Explicit drain of async global->LDS DMA (vmcnt) + LDS ops (lgkmcnt) BEFORE
// the barrier. Proven necessary in R4->R5: without it, warm graph replays hit
// a staging race (~2e-3 corruption). Keep at EVERY buffer handoff.
#define SYNC_DRAIN() do { \
  asm volatile("s_waitcnt vmcnt(0) lgkmcnt(0)" ::: "memory"); \
  __syncthreads(); \
} while (0)

// fp32 -> fp16 bits, round-to-nearest-even (v_cvt_f16_f32)
__device__ inline u16 f2h(float f) {
  union { _Float16 h; u16 u; } v;
  v.h = (_Float16)f;
  return v.u;
}

// fp16 bits -> fp32
__device__ inline float h2f(u16 u) {
  union { u16 u; _Float16 h; } v;
  v.u = u;
  return (float)v.h;
}

// async global -> LDS, 16B per lane (contiguous landing order only)
__device__ inline void gl2lds16(const void* g, void* l) {
  __builtin_amdgcn_global_load_lds(
      (const __attribute__((address_space(1))) unsigned int*)(unsigned long long)(uintptr_t)g,
      (__attribute__((address_space(3))) unsigned int*)(unsigned int)(uintptr_t)l,
      16, 0, 0);
}

// XOR chunk swizzle: within each 64-elem K-slice of a row, 16B chunk c of row
// r is stored at position c ^ (r & 7). gl2lds staging copies slices verbatim;
// fragment reads at chunk' = (kk*4+lg) ^ (l15&7) are phase-conflict-free.

// ---------------------------------------------------------------- cvt kernel
__global__ __launch_bounds__(256) void cvt_kernel(
    const float* __restrict__ x,
    const float* __restrict__ wq, const float* __restrict__ wk,
    const float* __restrict__ wv, const float* __restrict__ wo,
    u16* __restrict__ xb, u16* __restrict__ wqb, u16* __restrict__ wkb,
    u16* __restrict__ wvb, u16* __restrict__ wob) {
  const int y = blockIdx.y;
  const int Q = 1 << 20;
  const float* src;
  u16* dst;
  if (y < 4)       { src = x + y * Q; dst = xb + y * Q; }
  else if (y == 4) { src = wq; dst = wqb; }
  else if (y == 5) { src = wk; dst = wkb; }
  else if (y == 6) { src = wv; dst = wvb; }
  else             { src = wo; dst = wob; }
  const int i = (blockIdx.x * 256 + threadIdx.x) * 8;
  float4 a = *(const float4*)(src + i);
  float4 b = *(const float4*)(src + i + 4);
  short8 o;
  o[0] = (short)f2h(a.x); o[1] = (short)f2h(a.y);
  o[2] = (short)f2h(a.z); o[3] = (short)f2h(a.w);
  o[4] = (short)f2h(b.x); o[5] = (short)f2h(b.y);
  o[6] = (short)f2h(b.z); o[7] = (short)f2h(b.w);
  const int j = (i & ~63) | (((((i >> 3) & 7) ^ ((i >> 10) & 7))) << 3);
  *(short8*)(dst + j) = o;
}

// ------------------------------------------------------------ QKV projection
// Z-FUSED NT GEMM (unchanged, proven). 512 blocks, 80 KB LDS, 2 blocks/CU.
__global__ __launch_bounds__(256, 2) void gemm_qkv(
    const u16* __restrict__ xb,
    const u16* __restrict__ wqb, const u16* __restrict__ wkb, const u16* __restrict__ wvb,
    const float* __restrict__ bq, const float* __restrict__ bk, const float* __restrict__ bv,
    u16* __restrict__ qo, u16* __restrict__ ko, u16* __restrict__ vto) {
  __shared__ u16 smem[40960];        // As[2][8192] | Bs[2][3][4096] = 80 KB
  u16* As = smem;                    // + p*8192
  u16* Bs = smem + 16384;            // + p*12288 + z*4096
  const int tid = threadIdx.x, lane = tid & 63;
  const int wid = tid >> 6;
  const int l15 = lane & 15, lg = lane >> 4;
  const int m0 = blockIdx.y * 128, n0 = blockIdx.x * 64;
  const int sw = ((l15 & 7) << 3);
  const u16* Wz[3] = {wqb, wkb, wvb};

  f32x4 acc[3][2][4] = {};

#pragma unroll
  for (int i = 0; i < 4; ++i) {
    int c = i * 256 + tid;
    gl2lds16(xb + (m0 + (c >> 3)) * 1024 + (c & 7) * 8, As + c * 8);
  }
#pragma unroll
  for (int z = 0; z < 3; ++z)
#pragma unroll
    for (int i = 0; i < 2; ++i) {
      int c = i * 256 + tid;
      gl2lds16(Wz[z] + (n0 + (c >> 3)) * 1024 + (c & 7) * 8, Bs + z * 4096 + c * 8);
    }

  for (int k0 = 0; k0 < 1024; k0 += 64) {
    const int p = (k0 >> 6) & 1;
    SYNC_DRAIN();  // all waves' staging into buf p landed -> buf p ready
    if (k0 < 960) {
      u16* An = As + (1 - p) * 8192;
      u16* Bn = Bs + (1 - p) * 12288;
#pragma unroll
      for (int i = 0; i < 4; ++i) {
        int c = i * 256 + tid;
        gl2lds16(xb + (m0 + (c >> 3)) * 1024 + k0 + 64 + (c & 7) * 8, An + c * 8);
      }
#pragma unroll
      for (int z = 0; z < 3; ++z)
#pragma unroll
        for (int i = 0; i < 2; ++i) {
          int c = i * 256 + tid;
          gl2lds16(Wz[z] + (n0 + (c >> 3)) * 1024 + k0 + 64 + (c & 7) * 8, Bn + z * 4096 + c * 8);
        }
    }
    const u16* Ap = As + p * 8192;
    const u16* Bp = Bs + p * 12288;
#pragma unroll
    for (int kk = 0; kk < 2; ++kk) {
      half8 af[2], bf[3][4];
#pragma unroll
      for (int mb = 0; mb < 2; ++mb)
        af[mb] = *(const half8*)(Ap + (wid * 32 + mb * 16 + l15) * 64 + ((((kk * 4 + lg) << 3)) ^ sw));
#pragma unroll
      for (int z = 0; z < 3; ++z)
#pragma unroll
        for (int nb = 0; nb < 4; ++nb)
          bf[z][nb] = *(const half8*)(Bp + z * 4096 + (nb * 16 + l15) * 64 + ((((kk * 4 + lg) << 3)) ^ sw));
#pragma unroll
      for (int z = 0; z < 3; ++z)
#pragma unroll
        for (int mb = 0; mb < 2; ++mb)
#pragma unroll
          for (int nb = 0; nb < 4; ++nb)
            acc[z][mb][nb] = __builtin_amdgcn_mfma_f32_16x16x32_f16(af[mb], bf[z][nb], acc[z][mb][nb], 0, 0, 0);
    }
  }

  const float cexp = 0.18033688011112042f;  // log2(e)/8 folded into Q

  // Q epilogue (plain layout, pre-scaled)
#pragma unroll
  for (int mb = 0; mb < 2; ++mb)
#pragma unroll
    for (int nb = 0; nb < 4; ++nb)
#pragma unroll
      for (int r = 0; r < 4; ++r) {
        int m = m0 + wid * 32 + mb * 16 + lg * 4 + r;  // b*2048 + s
        int n = n0 + nb * 16 + l15;                    // h*64 + d
        float v = (acc[0][mb][nb][r] + bq[n]) * cexp;
        int b = m >> 11, s = m & 2047, hh = n >> 6, d = n & 63;
        qo[((b * 16 + hh) * 2048 + s) * 64 + d] = f2h(v);
      }

  // K epilogue (chunk-swizzled by s&7)
#pragma unroll
  for (int mb = 0; mb < 2; ++mb)
#pragma unroll
    for (int nb = 0; nb < 4; ++nb)
#pragma unroll
      for (int r = 0; r < 4; ++r) {
        int m = m0 + wid * 32 + mb * 16 + lg * 4 + r;
        int n = n0 + nb * 16 + l15;
        float v = acc[1][mb][nb][r] + bk[n];
        int b = m >> 11, s = m & 2047, hh = n >> 6, d = n & 63;
        int dcol = (((d >> 3) ^ (s & 7)) << 3) | (d & 7);
        ko[((b * 16 + hh) * 2048 + s) * 64 + dcol] = f2h(v);
      }

  // V epilogue (unchanged)
  SYNC_DRAIN();  // all waves done with As/Bs
  {
    u16* wbuf = smem + (wid >> 1) * 4608;
#pragma unroll
    for (int mb = 0; mb < 2; ++mb)
#pragma unroll
      for (int nb = 0; nb < 4; ++nb) {
        int n = n0 + nb * 16 + l15;
        float bn = bv[n];
        int dl = nb * 16 + l15;
#pragma unroll
        for (int r = 0; r < 4; ++r) {
          int sig = (wid & 1) * 32 + lg * 8 + mb * 4 + r;
          wbuf[dl * 72 + sig] = f2h(acc[2][mb][nb][r] + bn);
        }
      }
    SYNC_DRAIN();  // cross-wave transpose complete
    int hh = n0 >> 6;
    int bb = m0 >> 11;
    int sbase = m0 & 2047;
#pragma unroll
    for (int i = 0; i < 4; ++i) {
      int idx = i * 256 + tid;
      int p2 = idx >> 9, rem = idx & 511;
      int dl = rem >> 3, c = rem & 7;
      short8 vv = *(const short8*)(smem + p2 * 4608 + dl * 72 + c * 8);
      int cs = c ^ (dl & 7);
      *(short8*)(vto + ((bb * 16 + hh) * 64 + dl) * 2048 + sbase + p2 * 64 + cs * 8) = vv;
    }
  }
}

// ------------------------------------------------------- attention (partial)
// KT-SPLIT (flash-decoding): grid (16,16,4), z = b*2 + half; each block does
// 16 of the 32 kt tiles -> 1024 blocks = 4 blocks/CU, 16 waves/CU (was 8 from
// 2 lockstep blocks). No running max in this softmax (plain exp2, pre-scaled
// Q) so partials are ADDITIVE: block emits unnormalized O^T_half (fp16,
// packed [bh][d>>2][s][d&3] for coalesced 8B stores) and l_half (fp32).
// combine_kernel sums halves and normalizes. Per-thread staging (4 gl2lds/kt)
// and total K/V traffic (each tile staged once) unchanged vs R5 — the two R7
// failure modes are absent. Epilogue needs no SP transpose -> LDS 32 KB.
__global__ __launch_bounds__(256, 2) void attn_kernel(
    const u16* __restrict__ qg, const u16* __restrict__ kg,
    const u16* __restrict__ vtg, u16* __restrict__ po, float* __restrict__ pl) {
  const int h = blockIdx.x, qt = blockIdx.y;
  const int b = blockIdx.z >> 1, half = blockIdx.z & 1;
  const int bh = b * 16 + h;
  const int kbase = half * 16;
  const u16* Qg = qg + (bh * 2048 + qt * 128) * 64;
  const u16* Kg = kg + bh * 2048 * 64;
  const u16* Vg = vtg + bh * 64 * 2048;

  __shared__ u16 KV[2][8192];    // 32 KB: [p][0:4096)=K, [p][4096:8192)=V^T

  const int tid = threadIdx.x, lane = tid & 63, wid = tid >> 6;
  const int l15 = lane & 15, lg = lane >> 4;
  const int row0 = wid * 32;     // this wave's 32 query rows
  const int sw = ((l15 & 7) << 3);

  // Q fragments direct from global (pre-scaled; reused all 16 kt).
  half8 qf[2][2];
#pragma unroll
  for (int qtile = 0; qtile < 2; ++qtile)
#pragma unroll
    for (int kk = 0; kk < 2; ++kk)
      qf[qtile][kk] = *(const half8*)(Qg + (row0 + qtile * 16 + l15) * 64 + kk * 32 + lg * 8);

  half8 ones8;
#pragma unroll
  for (int j = 0; j < 8; ++j) ones8[j] = (_Float16)1.0f;

  // prologue: stage tile kbase into buffer 0
#pragma unroll
  for (int i = 0; i < 2; ++i) {
    int c = i * 256 + tid;
    gl2lds16(Kg + kbase * 4096 + c * 8, &KV[0][c * 8]);
    gl2lds16(Vg + (c >> 3) * 2048 + kbase * 64 + (c & 7) * 8, &KV[0][4096 + c * 8]);
  }

  f32x4 acc[4][2] = {};   // O^T: [dtile][qtile], C col = q = l15, row = d
  f32x4 accl[2] = {};     // l:  [qtile], all rows identical = l[q=l15]

  for (int it = 0; it < 16; ++it) {
    const int p = it & 1;
    SYNC_DRAIN();  // all waves' staging into buf p landed -> buf p ready
    if (it < 15) {
      const int ktn = kbase + it + 1;
#pragma unroll
      for (int i = 0; i < 2; ++i) {
        int c = i * 256 + tid;
        gl2lds16(Kg + ktn * 4096 + c * 8, &KV[1 - p][c * 8]);
        gl2lds16(Vg + (c >> 3) * 2048 + ktn * 64 + (c & 7) * 8, &KV[1 - p][4096 + c * 8]);
      }
    }
    const u16* Ks = &KV[p][0];
    const u16* Vts = &KV[p][4096];

    // S^T = K · Q^T : sc[ktile][qtile], C row = key = lg*4+r, col = q = l15
    f32x4 sc[4][2] = {};
#pragma unroll
    for (int kk = 0; kk < 2; ++kk) {
      half8 kf[4];
#pragma unroll
      for (int ktile = 0; ktile < 4; ++ktile)
        kf[ktile] = *(const half8*)(Ks + (ktile * 16 + l15) * 64 + ((((kk * 4 + lg) << 3)) ^ sw));
#pragma unroll
      for (int ktile = 0; ktile < 4; ++ktile)
#pragma unroll
        for (int qtile = 0; qtile < 2; ++qtile)
          sc[ktile][qtile] = __builtin_amdgcn_mfma_f32_16x16x32_f16(kf[ktile], qf[qtile][kk], sc[ktile][qtile], 0, 0, 0);
    }

    // P = exp2(S^T) packed in-register into B-operand fragments.
    half8 pf[2][2];  // [slice][qtile]
#pragma unroll
    for (int sl = 0; sl < 2; ++sl)
#pragma unroll
      for (int qtile = 0; qtile < 2; ++qtile) {
        union { half8 h; fp16x2 h2[4]; } pu;
        float a0 = EXP2F(sc[sl * 2][qtile][0]),     a1 = EXP2F(sc[sl * 2][qtile][1]);
        float a2 = EXP2F(sc[sl * 2][qtile][2]),     a3 = EXP2F(sc[sl * 2][qtile][3]);
        float b0 = EXP2F(sc[sl * 2 + 1][qtile][0]), b1 = EXP2F(sc[sl * 2 + 1][qtile][1]);
        float b2 = EXP2F(sc[sl * 2 + 1][qtile][2]), b3 = EXP2F(sc[sl * 2 + 1][qtile][3]);
        pu.h2[0] = __builtin_amdgcn_cvt_pkrtz(a0, a1);
        pu.h2[1] = __builtin_amdgcn_cvt_pkrtz(a2, a3);
        pu.h2[2] = __builtin_amdgcn_cvt_pkrtz(b0, b1);
        pu.h2[3] = __builtin_amdgcn_cvt_pkrtz(b2, b3);
        pf[sl][qtile] = pu.h;
      }

    // O^T += V^T · P ; l += 1 · P
#pragma unroll
    for (int sl = 0; sl < 2; ++sl) {
      half8 vf[4];
#pragma unroll
      for (int dtile = 0; dtile < 4; ++dtile)
        vf[dtile] = *(const half8*)(Vts + (dtile * 16 + l15) * 64 + ((((sl * 4 + lg) << 3)) ^ sw));
#pragma unroll
      for (int dtile = 0; dtile < 4; ++dtile)
#pragma unroll
        for (int qtile = 0; qtile < 2; ++qtile)
          acc[dtile][qtile] = __builtin_amdgcn_mfma_f32_16x16x32_f16(vf[dtile], pf[sl][qtile], acc[dtile][qtile], 0, 0, 0);
#pragma unroll
      for (int qtile = 0; qtile < 2; ++qtile)
        accl[qtile] = __builtin_amdgcn_mfma_f32_16x16x32_f16(ones8, pf[sl][qtile], accl[qtile], 0, 0, 0);
    }
  }

  // partial epilogue: unnormalized O^T as fp16, packed layout
  // po[(half*32+bh)*16 + dtile*4 + lg][s][r] : 8B/lane stores, 16 lanes
  // contiguous (128 B runs). l_half as fp32.
#pragma unroll
  for (int qtile = 0; qtile < 2; ++qtile) {
    int sg = qt * 128 + row0 + qtile * 16 + l15;
#pragma unroll
    for (int dtile = 0; dtile < 4; ++dtile) {
      ushort4v pk;
#pragma unroll
      for (int r = 0; r < 4; ++r)
        pk[r] = f2h(acc[dtile][qtile][r]);
      long idx = ((long)((half * 32 + bh) * 16 + dtile * 4 + lg)) * 8192 + sg * 4;
      *(ushort4v*)(po + idx) = pk;
    }
    if (lane < 16)
      pl[half * 65536 + bh * 2048 + qt * 128 + row0 + qtile * 16 + lane] = accl[qtile][0];
  }
}

// --------------------------------------------------------------- combine
// ctx[b,s,h*64+d] = (O0 + O1)[d,s] / (l0 + l1)[s], fp16, chunk-swizzled for
// gemm_out. Block = one (bh, 128-s window): stage both po half-tiles to LDS
// (coalesced gl2lds), transpose via scalar LDS reads, 16B swizzled stores.
__global__ __launch_bounds__(256) void combine_kernel(
    const u16* __restrict__ po, const float* __restrict__ pl,
    u16* __restrict__ ctxg) {
  __shared__ u16 L[2][8192];   // 32 KB: [half][d4*512 + sl*4 + r]
  const int bh = blockIdx.x, s0 = blockIdx.y * 128;
  const int tid = threadIdx.x;
  const int b = bh >> 4, h = bh & 15;

#pragma unroll
  for (int hf = 0; hf < 2; ++hf)
#pragma unroll
    for (int i = 0; i < 4; ++i) {
      int c = i * 256 + tid;           // c = d4*64 + local chunk
      gl2lds16(po + ((long)((hf * 32 + bh) * 16 + (c >> 6))) * 8192 + s0 * 4 + (c & 63) * 8,
               &L[hf][c * 8]);
    }
  SYNC_DRAIN();

  const int sl = tid >> 1, dbase = (tid & 1) * 32;
  const int sg = s0 + sl;
  float inv = 1.0f / (pl[bh * 2048 + sg] + pl[65536 + bh * 2048 + sg]);
  const int soff = (sl >> 1) * 8 + (sl & 1) * 4;   // == sl*4
#pragma unroll
  for (int j = 0; j < 4; ++j) {
    int d0 = dbase + j * 8;
    short8 o;
#pragma unroll
    for (int e = 0; e < 8; ++e) {
      int d = d0 + e;
      int li = (d >> 2) * 512 + soff + (d & 3);
      o[e] = (short)f2h((h2f(L[0][li]) + h2f(L[1][li])) * inv);
    }
    int c = d0 >> 3;
    int cs = c ^ (sg & 7);
    *(short8*)(ctxg + ((long)b * 2048 + sg) * 1024 + h * 64 + cs * 8) = o;
  }
}

// ------------------------------------------------------------ out projection
// R5's proven 64x64 form. grid (16,64) = 1024 blocks, 32 KB LDS.
__global__ __launch_bounds__(256) void gemm_out(
    const u16* __restrict__ cb, const u16* __restrict__ wob,
    const float* __restrict__ bo, float* __restrict__ out) {
  __shared__ u16 smem[16384];  // As[2][4096] | Bs[2][4096] = 32 KB
  u16* As = smem;
  u16* Bs = smem + 8192;
  const int tid = threadIdx.x, lane = tid & 63;
  const int wid = tid >> 6;
  const int l15 = lane & 15, lg = lane >> 4;
  const int m0 = blockIdx.y * 64, n0 = blockIdx.x * 64;
  const int sw = ((l15 & 7) << 3);

  f32x4 acc[4] = {};

#pragma unroll
  for (int i = 0; i < 2; ++i) {
    int c = i * 256 + tid;
    gl2lds16(cb  + (m0 + (c >> 3)) * 1024 + (c & 7) * 8, As + c * 8);
    gl2lds16(wob + (n0 + (c >> 3)) * 1024 + (c & 7) * 8, Bs + c * 8);
  }

  for (int k0 = 0; k0 < 1024; k0 += 64) {
    const int p = (k0 >> 6) & 1;
    SYNC_DRAIN();  // all waves' staging into buf p landed -> buf p ready
    if (k0 < 960) {
      u16* An = As + (1 - p) * 4096;
      u16* Bn = Bs + (1 - p) * 4096;
#pragma unroll
      for (int i = 0; i < 2; ++i) {
        int c = i * 256 + tid;
        gl2lds16(cb  + (m0 + (c >> 3)) * 1024 + k0 + 64 + (c & 7) * 8, An + c * 8);
        gl2lds16(wob + (n0 + (c >> 3)) * 1024 + k0 + 64 + (c & 7) * 8, Bn + c * 8);
      }
    }
    const u16* Ap = As + p * 4096;
    const u16* Bp = Bs + p * 4096;
#pragma unroll
    for (int kk = 0; kk < 2; ++kk) {
      half8 af, bf[4];
      af = *(const half8*)(Ap + (wid * 16 + l15) * 64 + ((((kk * 4 + lg) << 3)) ^ sw));
#pragma unroll
      for (int nb = 0; nb < 4; ++nb)
        bf[nb] = *(const half8*)(Bp + (nb * 16 + l15) * 64 + ((((kk * 4 + lg) << 3)) ^ sw));
#pragma unroll
      for (int nb = 0; nb < 4; ++nb)
        acc[nb] = __builtin_amdgcn_mfma_f32_16x16x32_f16(af, bf[nb], acc[nb], 0, 0, 0);
    }
  }

#pragma unroll
  for (int nb = 0; nb < 4; ++nb)
#pragma unroll
    for (int r = 0; r < 4; ++r) {
      int m = m0 + wid * 16 + lg * 4 + r;
      int n = n0 + nb * 16 + l15;
      out[m * 1024 + n] = acc[nb][r] + bo[n];
    }
}

// --------------------------------------------------------------------- launch
extern "C" void kernel_launch(void* const* d_in, const int* in_sizes, int n_in,
                              void* d_out, int out_size, void* d_ws, size_t ws_size,
                              hipStream_t stream) {
  const float* x  = (const float*)d_in[0];
  const float* wq = (const float*)d_in[1];
  const float* bq = (const float*)d_in[2];
  const float* wk = (const float*)d_in[3];
  const float* bk = (const float*)d_in[4];
  const float* wv = (const float*)d_in[5];
  const float* bv = (const float*)d_in[6];
  const float* wo = (const float*)d_in[7];
  const float* bo = (const float*)d_in[8];

  // 66 MB needed (partials live past the old 48 MB); harness ws = 256 MiB
  // (evidence: 268.5 MB fillBufferAligned per replay = workspace clear).
  if (ws_size < (size_t)66 * 1024 * 1024) return;
  u16* xb   = (u16*)d_ws;              // chunk-swizzled fp16
  u16* wqb  = xb  + (4u << 20);
  u16* wkb  = wqb + (1u << 20);
  u16* wvb  = wkb + (1u << 20);
  u16* wob  = wvb + (1u << 20);
  u16* qb   = wob + (1u << 20);        // plain [B,NH,S,D], pre-scaled fp16
  u16* kb   = qb  + (4u << 20);        // chunk-swizzled [B,NH,S,D] fp16
  u16* vtb  = kb  + (4u << 20);        // V^T [B,NH,D,Sperm], chunk-swizzled
  u16* ctxb = vtb + (4u << 20);        // chunk-swizzled [B,S,H] fp16
  u16* po   = ctxb + (4u << 20);       // partial O^T fp16 [2][32][16][2048][4]
  float* pl = (float*)(po + (8u << 20)); // partial l fp32 [2][32][2048]

  cvt_kernel<<<dim3(512, 8, 1), 256, 0, stream>>>(x, wq, wk, wv, wo, xb, wqb, wkb, wvb, wob);
  gemm_qkv<<<dim3(16, 32, 1), 256, 0, stream>>>(xb, wqb, wkb, wvb, bq, bk, bv, qb, kb, vtb);
  attn_kernel<<<dim3(16, 16, 4), 256, 0, stream>>>(qb, kb, vtb, po, pl);
  combine_kernel<<<dim3(32, 16, 1), 256, 0, stream>>>(po, pl, ctxb);
  gemm_out<<<dim3(16, 64, 1), 256, 0, stream>>>(ctxb, wob, bo, (float*)d_out);
}

// Round 10
// 174.807 us; speedup vs baseline: 1.0250x; 1.0089x over previous
//
#include <hip/hip_runtime.h>
#include <cstdint>

typedef unsigned short u16;
typedef __attribute__((ext_vector_type(8))) short short8;
typedef __attribute__((ext_vector_type(8))) _Float16 half8;
typedef __attribute__((ext_vector_type(2))) __fp16 fp16x2;   // cvt_pkrtz return type
typedef __attribute__((ext_vector_type(4))) float f32x4;
typedef __attribute__((ext_vector_type(4))) unsigned short ushort4v;

#if __has_builtin(__builtin_amdgcn_exp2f)
#define EXP2F(x) __builtin_amdgcn_exp2f(x)
#else
#define EXP2F(x) exp2f(x)
#endif

// Explicit drain of async global->LDS DMA (vmcnt) + LDS ops (lgkmcnt) BEFORE
// the barrier. Proven necessary in R4->R5: without it, warm graph replays hit
// a staging race (~2e-3 corruption). Keep at EVERY buffer handoff.
#define SYNC_DRAIN() do { \
  asm volatile("s_waitcnt vmcnt(0) lgkmcnt(0)" ::: "memory"); \
  __syncthreads(); \
} while (0)

// fp32 -> fp16 bits, round-to-nearest-even (v_cvt_f16_f32)
__device__ inline u16 f2h(float f) {
  union { _Float16 h; u16 u; } v;
  v.h = (_Float16)f;
  return v.u;
}

// async global -> LDS, 16B per lane (contiguous landing order only)
__device__ inline void gl2lds16(const void* g, void* l) {
  __builtin_amdgcn_global_load_lds(
      (const __attribute__((address_space(1))) unsigned int*)(unsigned long long)(uintptr_t)g,
      (__attribute__((address_space(3))) unsigned int*)(unsigned int)(uintptr_t)l,
      16, 0, 0);
}

// XOR chunk swizzle: within each 64-elem K-slice of a row, 16B chunk c of row
// r is stored at position c ^ (r & 7). gl2lds staging copies slices verbatim;
// fragment reads at chunk' = (kk*4+lg) ^ (l15&7) are phase-conflict-free.

// ---------------------------------------------------------------- cvt kernel
__global__ __launch_bounds__(256) void cvt_kernel(
    const float* __restrict__ x,
    const float* __restrict__ wq, const float* __restrict__ wk,
    const float* __restrict__ wv, const float* __restrict__ wo,
    u16* __restrict__ xb, u16* __restrict__ wqb, u16* __restrict__ wkb,
    u16* __restrict__ wvb, u16* __restrict__ wob) {
  const int y = blockIdx.y;
  const int Q = 1 << 20;
  const float* src;
  u16* dst;
  if (y < 4)       { src = x + y * Q; dst = xb + y * Q; }
  else if (y == 4) { src = wq; dst = wqb; }
  else if (y == 5) { src = wk; dst = wkb; }
  else if (y == 6) { src = wv; dst = wvb; }
  else             { src = wo; dst = wob; }
  const int i = (blockIdx.x * 256 + threadIdx.x) * 8;
  float4 a = *(const float4*)(src + i);
  float4 b = *(const float4*)(src + i + 4);
  short8 o;
  o[0] = (short)f2h(a.x); o[1] = (short)f2h(a.y);
  o[2] = (short)f2h(a.z); o[3] = (short)f2h(a.w);
  o[4] = (short)f2h(b.x); o[5] = (short)f2h(b.y);
  o[6] = (short)f2h(b.z); o[7] = (short)f2h(b.w);
  const int j = (i & ~63) | (((((i >> 3) & 7) ^ ((i >> 10) & 7))) << 3);
  *(short8*)(dst + j) = o;
}

// ------------------------------------------------------------ QKV projection
// Z-FUSED NT GEMM (unchanged, proven). 512 blocks, 80 KB LDS, 2 blocks/CU.
__global__ __launch_bounds__(256, 2) void gemm_qkv(
    const u16* __restrict__ xb,
    const u16* __restrict__ wqb, const u16* __restrict__ wkb, const u16* __restrict__ wvb,
    const float* __restrict__ bq, const float* __restrict__ bk, const float* __restrict__ bv,
    u16* __restrict__ qo, u16* __restrict__ ko, u16* __restrict__ vto) {
  __shared__ u16 smem[40960];        // As[2][8192] | Bs[2][3][4096] = 80 KB
  u16* As = smem;                    // + p*8192
  u16* Bs = smem + 16384;            // + p*12288 + z*4096
  const int tid = threadIdx.x, lane = tid & 63;
  const int wid = tid >> 6;
  const int l15 = lane & 15, lg = lane >> 4;
  const int m0 = blockIdx.y * 128, n0 = blockIdx.x * 64;
  const int sw = ((l15 & 7) << 3);
  const u16* Wz[3] = {wqb, wkb, wvb};

  f32x4 acc[3][2][4] = {};

#pragma unroll
  for (int i = 0; i < 4; ++i) {
    int c = i * 256 + tid;
    gl2lds16(xb + (m0 + (c >> 3)) * 1024 + (c & 7) * 8, As + c * 8);
  }
#pragma unroll
  for (int z = 0; z < 3; ++z)
#pragma unroll
    for (int i = 0; i < 2; ++i) {
      int c = i * 256 + tid;
      gl2lds16(Wz[z] + (n0 + (c >> 3)) * 1024 + (c & 7) * 8, Bs + z * 4096 + c * 8);
    }

  for (int k0 = 0; k0 < 1024; k0 += 64) {
    const int p = (k0 >> 6) & 1;
    SYNC_DRAIN();  // all waves' staging into buf p landed -> buf p ready
    if (k0 < 960) {
      u16* An = As + (1 - p) * 8192;
      u16* Bn = Bs + (1 - p) * 12288;
#pragma unroll
      for (int i = 0; i < 4; ++i) {
        int c = i * 256 + tid;
        gl2lds16(xb + (m0 + (c >> 3)) * 1024 + k0 + 64 + (c & 7) * 8, An + c * 8);
      }
#pragma unroll
      for (int z = 0; z < 3; ++z)
#pragma unroll
        for (int i = 0; i < 2; ++i) {
          int c = i * 256 + tid;
          gl2lds16(Wz[z] + (n0 + (c >> 3)) * 1024 + k0 + 64 + (c & 7) * 8, Bn + z * 4096 + c * 8);
        }
    }
    const u16* Ap = As + p * 8192;
    const u16* Bp = Bs + p * 12288;
#pragma unroll
    for (int kk = 0; kk < 2; ++kk) {
      half8 af[2], bf[3][4];
#pragma unroll
      for (int mb = 0; mb < 2; ++mb)
        af[mb] = *(const half8*)(Ap + (wid * 32 + mb * 16 + l15) * 64 + ((((kk * 4 + lg) << 3)) ^ sw));
#pragma unroll
      for (int z = 0; z < 3; ++z)
#pragma unroll
        for (int nb = 0; nb < 4; ++nb)
          bf[z][nb] = *(const half8*)(Bp + z * 4096 + (nb * 16 + l15) * 64 + ((((kk * 4 + lg) << 3)) ^ sw));
#pragma unroll
      for (int z = 0; z < 3; ++z)
#pragma unroll
        for (int mb = 0; mb < 2; ++mb)
#pragma unroll
          for (int nb = 0; nb < 4; ++nb)
            acc[z][mb][nb] = __builtin_amdgcn_mfma_f32_16x16x32_f16(af[mb], bf[z][nb], acc[z][mb][nb], 0, 0, 0);
    }
  }

  const float cexp = 0.18033688011112042f;  // log2(e)/8 folded into Q

  // Q epilogue (plain layout, pre-scaled)
#pragma unroll
  for (int mb = 0; mb < 2; ++mb)
#pragma unroll
    for (int nb = 0; nb < 4; ++nb)
#pragma unroll
      for (int r = 0; r < 4; ++r) {
        int m = m0 + wid * 32 + mb * 16 + lg * 4 + r;  // b*2048 + s
        int n = n0 + nb * 16 + l15;                    // h*64 + d
        float v = (acc[0][mb][nb][r] + bq[n]) * cexp;
        int b = m >> 11, s = m & 2047, hh = n >> 6, d = n & 63;
        qo[((b * 16 + hh) * 2048 + s) * 64 + d] = f2h(v);
      }

  // K epilogue (chunk-swizzled by s&7)
#pragma unroll
  for (int mb = 0; mb < 2; ++mb)
#pragma unroll
    for (int nb = 0; nb < 4; ++nb)
#pragma unroll
      for (int r = 0; r < 4; ++r) {
        int m = m0 + wid * 32 + mb * 16 + lg * 4 + r;
        int n = n0 + nb * 16 + l15;
        float v = acc[1][mb][nb][r] + bk[n];
        int b = m >> 11, s = m & 2047, hh = n >> 6, d = n & 63;
        int dcol = (((d >> 3) ^ (s & 7)) << 3) | (d & 7);
        ko[((b * 16 + hh) * 2048 + s) * 64 + dcol] = f2h(v);
      }

  // V epilogue (unchanged)
  SYNC_DRAIN();  // all waves done with As/Bs
  {
    u16* wbuf = smem + (wid >> 1) * 4608;
#pragma unroll
    for (int mb = 0; mb < 2; ++mb)
#pragma unroll
      for (int nb = 0; nb < 4; ++nb) {
        int n = n0 + nb * 16 + l15;
        float bn = bv[n];
        int dl = nb * 16 + l15;
#pragma unroll
        for (int r = 0; r < 4; ++r) {
          int sig = (wid & 1) * 32 + lg * 8 + mb * 4 + r;
          wbuf[dl * 72 + sig] = f2h(acc[2][mb][nb][r] + bn);
        }
      }
    SYNC_DRAIN();  // cross-wave transpose complete
    int hh = n0 >> 6;
    int bb = m0 >> 11;
    int sbase = m0 & 2047;
#pragma unroll
    for (int i = 0; i < 4; ++i) {
      int idx = i * 256 + tid;
      int p2 = idx >> 9, rem = idx & 511;
      int dl = rem >> 3, c = rem & 7;
      short8 vv = *(const short8*)(smem + p2 * 4608 + dl * 72 + c * 8);
      int cs = c ^ (dl & 7);
      *(short8*)(vto + ((bb * 16 + hh) * 64 + dl) * 2048 + sbase + p2 * 64 + cs * 8) = vv;
    }
  }
}

// ---------------------------------------------------------------- attention
// TRAFFIC-HALVED: R9 post-mortem showed attn is bound by K/V staging traffic
// (~10 B/cyc/CU delivery ceiling; 268 MB staged -> 44 us; occupancy changes
// were no-ops, R7's 2x traffic -> 54 us). Each block now processes 256 q-rows
// (2 q-groups, G loop) against each staged K/V tile: staged bytes 268->134 MB.
// grid (16,8,2) = 256 blocks (1/CU — fine: streaming-BW-bound, double-
// buffered prefetch). Math per q-row is BIT-IDENTICAL to R5 (same op order).
// Epilogue: two 128-row SP passes over the 18 KB overlay, R4 fence discipline.
__global__ __launch_bounds__(256, 1) void attn_kernel(
    const u16* __restrict__ qg, const u16* __restrict__ kg,
    const u16* __restrict__ vtg, u16* __restrict__ ctxg) {
  const int h = blockIdx.x, qt = blockIdx.y, b = blockIdx.z;
  const int bh = b * 16 + h;
  const u16* Qg = qg + (bh * 2048 + qt * 256) * 64;
  const u16* Kg = kg + bh * 2048 * 64;
  const u16* Vg = vtg + bh * 64 * 2048;

  __shared__ u16 KV[2][8192];    // 32 KB: [p][0:4096)=K, [p][4096:8192)=V^T
  u16* SP = &KV[0][0];           // epilogue overlay: 128*72 u16 = 18 KB

  const int tid = threadIdx.x, lane = tid & 63, wid = tid >> 6;
  const int l15 = lane & 15, lg = lane >> 4;
  const int row0 = wid * 32;     // this wave's 32 rows within a 128-row group
  const int sw = ((l15 & 7) << 3);

  // Q fragments for both 128-row groups (pre-scaled; reused all 32 kt).
  half8 qf[2][2][2];  // [g][qtile][kk]
#pragma unroll
  for (int g = 0; g < 2; ++g)
#pragma unroll
    for (int qtile = 0; qtile < 2; ++qtile)
#pragma unroll
      for (int kk = 0; kk < 2; ++kk)
        qf[g][qtile][kk] = *(const half8*)(Qg + (g * 128 + row0 + qtile * 16 + l15) * 64 + kk * 32 + lg * 8);

  half8 ones8;
#pragma unroll
  for (int j = 0; j < 8; ++j) ones8[j] = (_Float16)1.0f;

  // prologue: stage kt=0 into buffer 0
#pragma unroll
  for (int i = 0; i < 2; ++i) {
    int c = i * 256 + tid;
    gl2lds16(Kg + c * 8, &KV[0][c * 8]);
    gl2lds16(Vg + (c >> 3) * 2048 + (c & 7) * 8, &KV[0][4096 + c * 8]);
  }

  f32x4 acc[2][4][2] = {};   // [g][dtile][qtile]: O^T, C col = q = l15
  f32x4 accl[2][2] = {};     // [g][qtile]: l

  for (int kt = 0; kt < 32; ++kt) {
    const int p = kt & 1;
    SYNC_DRAIN();  // all waves' staging into buf p landed -> buf p ready
    if (kt < 31) {
#pragma unroll
      for (int i = 0; i < 2; ++i) {
        int c = i * 256 + tid;
        gl2lds16(Kg + (kt + 1) * 4096 + c * 8, &KV[1 - p][c * 8]);
        gl2lds16(Vg + (c >> 3) * 2048 + (kt + 1) * 64 + (c & 7) * 8, &KV[1 - p][4096 + c * 8]);
      }
    }
    const u16* Ks = &KV[p][0];
    const u16* Vts = &KV[p][4096];

#pragma unroll
    for (int g = 0; g < 2; ++g) {
      // S^T = K · Q^T : sc[ktile][qtile], C row = key = lg*4+r, col = q = l15
      f32x4 sc[4][2] = {};
#pragma unroll
      for (int kk = 0; kk < 2; ++kk) {
        half8 kf[4];
#pragma unroll
        for (int ktile = 0; ktile < 4; ++ktile)
          kf[ktile] = *(const half8*)(Ks + (ktile * 16 + l15) * 64 + ((((kk * 4 + lg) << 3)) ^ sw));
#pragma unroll
        for (int ktile = 0; ktile < 4; ++ktile)
#pragma unroll
          for (int qtile = 0; qtile < 2; ++qtile)
            sc[ktile][qtile] = __builtin_amdgcn_mfma_f32_16x16x32_f16(kf[ktile], qf[g][qtile][kk], sc[ktile][qtile], 0, 0, 0);
      }

      // P = exp2(S^T) packed in-register into B-operand fragments.
      half8 pf[2][2];  // [slice][qtile]
#pragma unroll
      for (int sl = 0; sl < 2; ++sl)
#pragma unroll
        for (int qtile = 0; qtile < 2; ++qtile) {
          union { half8 h; fp16x2 h2[4]; } pu;
          float a0 = EXP2F(sc[sl * 2][qtile][0]),     a1 = EXP2F(sc[sl * 2][qtile][1]);
          float a2 = EXP2F(sc[sl * 2][qtile][2]),     a3 = EXP2F(sc[sl * 2][qtile][3]);
          float b0 = EXP2F(sc[sl * 2 + 1][qtile][0]), b1 = EXP2F(sc[sl * 2 + 1][qtile][1]);
          float b2 = EXP2F(sc[sl * 2 + 1][qtile][2]), b3 = EXP2F(sc[sl * 2 + 1][qtile][3]);
          pu.h2[0] = __builtin_amdgcn_cvt_pkrtz(a0, a1);
          pu.h2[1] = __builtin_amdgcn_cvt_pkrtz(a2, a3);
          pu.h2[2] = __builtin_amdgcn_cvt_pkrtz(b0, b1);
          pu.h2[3] = __builtin_amdgcn_cvt_pkrtz(b2, b3);
          pf[sl][qtile] = pu.h;
        }

      // O^T += V^T · P ; l += 1 · P
#pragma unroll
      for (int sl = 0; sl < 2; ++sl) {
        half8 vf[4];
#pragma unroll
        for (int dtile = 0; dtile < 4; ++dtile)
          vf[dtile] = *(const half8*)(Vts + (dtile * 16 + l15) * 64 + ((((sl * 4 + lg) << 3)) ^ sw));
#pragma unroll
        for (int dtile = 0; dtile < 4; ++dtile)
#pragma unroll
          for (int qtile = 0; qtile < 2; ++qtile)
            acc[g][dtile][qtile] = __builtin_amdgcn_mfma_f32_16x16x32_f16(vf[dtile], pf[sl][qtile], acc[g][dtile][qtile], 0, 0, 0);
#pragma unroll
        for (int qtile = 0; qtile < 2; ++qtile)
          accl[g][qtile] = __builtin_amdgcn_mfma_f32_16x16x32_f16(ones8, pf[sl][qtile], accl[g][qtile], 0, 0, 0);
      }
    }
  }

  // epilogue: KV dead; SP (128x72) overlays it. Two 128-row passes, each
  // barrier-fenced (R4 discipline: drain between differently-typed W/R).
  SYNC_DRAIN();  // all waves finished reading KV (last tile) before overlay
#pragma unroll
  for (int g = 0; g < 2; ++g) {
    if (g) SYNC_DRAIN();  // pass-0 SP reads complete before rewrite
#pragma unroll
    for (int qtile = 0; qtile < 2; ++qtile) {
      float inv = 1.0f / accl[g][qtile][0];
#pragma unroll
      for (int dtile = 0; dtile < 4; ++dtile) {
        ushort4v pk;
#pragma unroll
        for (int r = 0; r < 4; ++r)
          pk[r] = f2h(acc[g][dtile][qtile][r] * inv);   // d = dtile*16 + lg*4 + r
        *(ushort4v*)(SP + (row0 + qtile * 16 + l15) * 72 + dtile * 16 + lg * 4) = pk;
      }
    }
    SYNC_DRAIN();  // SP writes must land before differently-typed reads
#pragma unroll
    for (int i = 0; i < 4; ++i) {
      int idx = i * 64 + lane;               // 256 chunks/wave = 32 rows x 8
      int rl = idx >> 3, c = idx & 7;
      short8 vv = *(const short8*)(SP + (row0 + rl) * 72 + c * 8);
      int s = qt * 256 + g * 128 + row0 + rl;
      int cs = c ^ (s & 7);                  // chunk swizzle by s&7 for gemm_out
      *(short8*)(ctxg + ((long)b * 2048 + s) * 1024 + h * 64 + cs * 8) = vv;
    }
  }
}

// ------------------------------------------------------------ out projection
// R5's proven 64x64 form. grid (16,64) = 1024 blocks, 32 KB LDS.
__global__ __launch_bounds__(256) void gemm_out(
    const u16* __restrict__ cb, const u16* __restrict__ wob,
    const float* __restrict__ bo, float* __restrict__ out) {
  __shared__ u16 smem[16384];  // As[2][4096] | Bs[2][4096] = 32 KB
  u16* As = smem;
  u16* Bs = smem + 8192;
  const int tid = threadIdx.x, lane = tid & 63;
  const int wid = tid >> 6;
  const int l15 = lane & 15, lg = lane >> 4;
  const int m0 = blockIdx.y * 64, n0 = blockIdx.x * 64;
  const int sw = ((l15 & 7) << 3);

  f32x4 acc[4] = {};

#pragma unroll
  for (int i = 0; i < 2; ++i) {
    int c = i * 256 + tid;
    gl2lds16(cb  + (m0 + (c >> 3)) * 1024 + (c & 7) * 8, As + c * 8);
    gl2lds16(wob + (n0 + (c >> 3)) * 1024 + (c & 7) * 8, Bs + c * 8);
  }

  for (int k0 = 0; k0 < 1024; k0 += 64) {
    const int p = (k0 >> 6) & 1;
    SYNC_DRAIN();  // all waves' staging into buf p landed -> buf p ready
    if (k0 < 960) {
      u16* An = As + (1 - p) * 4096;
      u16* Bn = Bs + (1 - p) * 4096;
#pragma unroll
      for (int i = 0; i < 2; ++i) {
        int c = i * 256 + tid;
        gl2lds16(cb  + (m0 + (c >> 3)) * 1024 + k0 + 64 + (c & 7) * 8, An + c * 8);
        gl2lds16(wob + (n0 + (c >> 3)) * 1024 + k0 + 64 + (c & 7) * 8, Bn + c * 8);
      }
    }
    const u16* Ap = As + p * 4096;
    const u16* Bp = Bs + p * 4096;
#pragma unroll
    for (int kk = 0; kk < 2; ++kk) {
      half8 af, bf[4];
      af = *(const half8*)(Ap + (wid * 16 + l15) * 64 + ((((kk * 4 + lg) << 3)) ^ sw));
#pragma unroll
      for (int nb = 0; nb < 4; ++nb)
        bf[nb] = *(const half8*)(Bp + (nb * 16 + l15) * 64 + ((((kk * 4 + lg) << 3)) ^ sw));
#pragma unroll
      for (int nb = 0; nb < 4; ++nb)
        acc[nb] = __builtin_amdgcn_mfma_f32_16x16x32_f16(af, bf[nb], acc[nb], 0, 0, 0);
    }
  }

#pragma unroll
  for (int nb = 0; nb < 4; ++nb)
#pragma unroll
    for (int r = 0; r < 4; ++r) {
      int m = m0 + wid * 16 + lg * 4 + r;
      int n = n0 + nb * 16 + l15;
      out[m * 1024 + n] = acc[nb][r] + bo[n];
    }
}

// --------------------------------------------------------------------- launch
extern "C" void kernel_launch(void* const* d_in, const int* in_sizes, int n_in,
                              void* d_out, int out_size, void* d_ws, size_t ws_size,
                              hipStream_t stream) {
  const float* x  = (const float*)d_in[0];
  const float* wq = (const float*)d_in[1];
  const float* bq = (const float*)d_in[2];
  const float* wk = (const float*)d_in[3];
  const float* bk = (const float*)d_in[4];
  const float* wv = (const float*)d_in[5];
  const float* bv = (const float*)d_in[6];
  const float* wo = (const float*)d_in[7];
  const float* bo = (const float*)d_in[8];

  if (ws_size < (size_t)24 * 1024 * 1024 * 2) return;
  u16* xb   = (u16*)d_ws;              // chunk-swizzled fp16
  u16* wqb  = xb  + (4u << 20);
  u16* wkb  = wqb + (1u << 20);
  u16* wvb  = wkb + (1u << 20);
  u16* wob  = wvb + (1u << 20);
  u16* qb   = wob + (1u << 20);        // plain [B,NH,S,D], pre-scaled fp16
  u16* kb   = qb  + (4u << 20);        // chunk-swizzled [B,NH,S,D] fp16
  u16* vtb  = kb  + (4u << 20);        // V^T [B,NH,D,Sperm], chunk-swizzled
  u16* ctxb = vtb + (4u << 20);        // chunk-swizzled [B,S,H] fp16

  cvt_kernel<<<dim3(512, 8, 1), 256, 0, stream>>>(x, wq, wk, wv, wo, xb, wqb, wkb, wvb, wob);
  gemm_qkv<<<dim3(16, 32, 1), 256, 0, stream>>>(xb, wqb, wkb, wvb, bq, bk, bv, qb, kb, vtb);
  attn_kernel<<<dim3(16, 8, 2), 256, 0, stream>>>(qb, kb, vtb, ctxb);
  gemm_out<<<dim3(16, 64, 1), 256, 0, stream>>>(ctxb, wob, bo, (float*)d_out);
}